// Round 1
// baseline (16019.086 us; speedup 1.0000x reference)
//
#include <hip/hip_runtime.h>
#include <hip/hip_bf16.h>
#include <math.h>

namespace {

constexpr int Bc  = 8;
constexpr int Lc  = 2048;
constexpr int VOC = 1969;
constexpr int DM  = 768;
constexpr int DI  = 1536;
constexpr int DS  = 16;
constexpr int DC  = 4;
constexpr int DR  = 48;
constexpr int M   = Bc * Lc;          // 16384 rows
constexpr float EPS_ = 1e-5f;

__device__ __forceinline__ float siluf(float x) { return x / (1.f + __expf(-x)); }

// h[row,d] = embed[ids[row]][d] + times[row]*time_w[d] + time_b[d]
__global__ void k_embed(const int* __restrict__ ids, const float* __restrict__ times,
                        const float* __restrict__ emb, const float* __restrict__ tw,
                        const float* __restrict__ tb, float* __restrict__ h) {
  int row = blockIdx.x;
  int id  = ids[row];
  float tv = times[row];
  const float* e = emb + (size_t)id * DM;
  for (int d = threadIdx.x; d < DM; d += blockDim.x)
    h[(size_t)row * DM + d] = e[d] + tv * tw[d] + tb[d];
}

// o[row,:] = x[row,:] * rsqrt(mean(x^2)+eps) * w    (one 256-thread block per row, DM=768=3*256)
__global__ __launch_bounds__(256) void k_rmsnorm(const float* __restrict__ x,
                                                 const float* __restrict__ w,
                                                 float* __restrict__ o) {
  int row = blockIdx.x;
  const float* xr = x + (size_t)row * DM;
  float v[3];
  float s = 0.f;
#pragma unroll
  for (int i = 0; i < 3; i++) { v[i] = xr[threadIdx.x + 256 * i]; s += v[i] * v[i]; }
#pragma unroll
  for (int off = 32; off > 0; off >>= 1) s += __shfl_down(s, off);
  __shared__ float red[4];
  int lane = threadIdx.x & 63, wv = threadIdx.x >> 6;
  if (lane == 0) red[wv] = s;
  __syncthreads();
  if (threadIdx.x == 0)
    red[0] = rsqrtf((red[0] + red[1] + red[2] + red[3]) / (float)DM + EPS_);
  __syncthreads();
  float sc = red[0];
#pragma unroll
  for (int i = 0; i < 3; i++) {
    int d = threadIdx.x + 256 * i;
    o[(size_t)row * DM + d] = v[i] * sc * w[d];
  }
}

// Depthwise causal conv (width 4) + bias + silu.
// xz row stride is 2*DI (x is the first DI columns); out is dense [M][DI].
__global__ __launch_bounds__(256) void k_conv(const float* __restrict__ xz,
                                              const float* __restrict__ cwt,
                                              const float* __restrict__ cbv,
                                              float* __restrict__ xo) {
  size_t idx = (size_t)blockIdx.x * blockDim.x + threadIdx.x;
  if (idx >= (size_t)M * DI) return;
  int d = (int)(idx % DI);
  size_t row = idx / DI;
  int t = (int)(row % Lc);
  size_t b = row / Lc;
  float acc = cbv[d];
#pragma unroll
  for (int j = 0; j < DC; j++) {
    int tt = t - (DC - 1) + j;
    if (tt >= 0) acc += cwt[d * DC + j] * xz[((size_t)b * Lc + tt) * (2 * DI) + d];
  }
  xo[idx] = siluf(acc);
}

// C[M x N] = act( A[M x K] * W[N x K]^T + bias ), optional += into C.
// 64x64 tile, K-step 16, 256 threads, 4x4 acc per thread. M==16384, K%16==0.
__global__ __launch_bounds__(256) void k_gemm_nt(
    const float* __restrict__ A, int lda,
    const float* __restrict__ W,
    const float* __restrict__ bias,
    float* __restrict__ C, int ldc,
    int N, int K, int act, int resAdd) {
  __shared__ float As[16][68];   // [k][m], 68-float row stride keeps 16B alignment
  __shared__ float Ws[16][68];   // [k][n]
  int tid = threadIdx.x;
  int bm = blockIdx.x << 6, bn = blockIdx.y << 6;
  int tx = tid & 15, ty = tid >> 4;
  int lrow = tid >> 2, lkk = (tid & 3) << 2;
  const float* Ap = A + (size_t)(bm + lrow) * lda + lkk;
  bool wok = (bn + lrow) < N;
  const float* Wp = W + (size_t)(bn + lrow) * K + lkk;
  float acc[4][4] = {};
  for (int k0 = 0; k0 < K; k0 += 16) {
    float4 av = *(const float4*)(Ap + k0);
    float4 wv = wok ? *(const float4*)(Wp + k0) : make_float4(0.f, 0.f, 0.f, 0.f);
    As[lkk + 0][lrow] = av.x; As[lkk + 1][lrow] = av.y;
    As[lkk + 2][lrow] = av.z; As[lkk + 3][lrow] = av.w;
    Ws[lkk + 0][lrow] = wv.x; Ws[lkk + 1][lrow] = wv.y;
    Ws[lkk + 2][lrow] = wv.z; Ws[lkk + 3][lrow] = wv.w;
    __syncthreads();
#pragma unroll
    for (int k = 0; k < 16; k++) {
      float a[4], b[4];
#pragma unroll
      for (int i = 0; i < 4; i++) a[i] = As[k][ty * 4 + i];
#pragma unroll
      for (int j = 0; j < 4; j++) b[j] = Ws[k][tx * 4 + j];
#pragma unroll
      for (int i = 0; i < 4; i++)
#pragma unroll
        for (int j = 0; j < 4; j++) acc[i][j] += a[i] * b[j];
    }
    __syncthreads();
  }
#pragma unroll
  for (int i = 0; i < 4; i++) {
    int m = bm + ty * 4 + i;
#pragma unroll
    for (int j = 0; j < 4; j++) {
      int n = bn + tx * 4 + j;
      if (n < N) {
        float v = acc[i][j];
        if (bias) v += bias[n];
        if (act == 1) v = (v > 20.f) ? v : log1pf(__expf(v));  // softplus
        size_t off = (size_t)m * ldc + n;
        if (resAdd) C[off] += v; else C[off] = v;
      }
    }
  }
}

// Selective scan. One thread per (b, d, n): 16 lanes per (b,d) group.
// delta lives in the x-half of xz (stride 2*DI); u lives in u_y (dense DI) and
// is overwritten in place with y * silu(z).
__global__ __launch_bounds__(256) void k_scan(
    const float* __restrict__ dlt_buf,   // [M][2*DI], delta at col d
    const float* __restrict__ xdbl,      // [M][80], B at 48+n, C at 64+n
    const float* __restrict__ xz,        // [M][2*DI], z at DI+d
    const float* __restrict__ alog,      // [DI][DS]
    const float* __restrict__ dsk,       // [DI]
    float* __restrict__ u_y) {           // [M][DI] in: u, out: y*silu(z)
  int g = blockIdx.x * (blockDim.x >> 4) + (threadIdx.x >> 4);
  int n = threadIdx.x & 15;
  int b = g / DI, d = g % DI;
  float Av = -__expf(alog[d * DS + n]);
  float Dv = dsk[d];
  float hs = 0.f;
  const float* dp = dlt_buf + (size_t)b * Lc * (2 * DI) + d;
  const float* zp = xz + (size_t)b * Lc * (2 * DI) + DI + d;
  const float* bp = xdbl + (size_t)b * Lc * 80 + DR + n;
  const float* cp = bp + DS;
  float* up = u_y + (size_t)b * Lc * DI + d;
  for (int t = 0; t < Lc; t++) {
    float dlt = dp[(size_t)t * (2 * DI)];
    float u   = up[(size_t)t * DI];
    float Bt  = bp[(size_t)t * 80];
    float Ct  = cp[(size_t)t * 80];
    hs = hs * __expf(dlt * Av) + (dlt * u) * Bt;
    float p = hs * Ct;
    p += __shfl_xor(p, 1);
    p += __shfl_xor(p, 2);
    p += __shfl_xor(p, 4);
    p += __shfl_xor(p, 8);
    if (n == 0) {
      float y = p + u * Dv;
      float z = zp[(size_t)t * (2 * DI)];
      up[(size_t)t * DI] = y * siluf(z);
    }
  }
}

}  // namespace

extern "C" void kernel_launch(void* const* d_in, const int* in_sizes, int n_in,
                              void* d_out, int out_size, void* d_ws, size_t ws_size,
                              hipStream_t stream) {
  const int*   ids   = (const int*)d_in[0];
  const float* times = (const float*)d_in[1];
  // d_in[2] attention_mask: all ones, unused
  const float* emb   = (const float*)d_in[3];
  const float* tw    = (const float*)d_in[4];
  const float* tb    = (const float*)d_in[5];
  const float* inw   = (const float*)d_in[6];
  const float* cw    = (const float*)d_in[7];
  const float* cb    = (const float*)d_in[8];
  const float* xw    = (const float*)d_in[9];
  const float* dtw   = (const float*)d_in[10];
  const float* dtb   = (const float*)d_in[11];
  const float* alog  = (const float*)d_in[12];
  const float* dsk   = (const float*)d_in[13];
  const float* ow    = (const float*)d_in[14];
  const float* nw    = (const float*)d_in[15];
  const float* nfw   = (const float*)d_in[16];
  float* out = (float*)d_out;

  // Workspace layout (floats): h, hn, xz, xc, xdbl  -> ~407 MB total
  float* ws   = (float*)d_ws;
  float* h    = ws;  ws += (size_t)M * DM;
  float* hn   = ws;  ws += (size_t)M * DM;
  float* xz   = ws;  ws += (size_t)M * (2 * DI);
  float* xc   = ws;  ws += (size_t)M * DI;
  float* xdbl = ws;  ws += (size_t)M * (DR + 2 * DS);

  k_embed<<<M, 256, 0, stream>>>(ids, times, emb, tw, tb, h);

  for (int i = 0; i < 4; i++) {
    k_rmsnorm<<<M, 256, 0, stream>>>(h, nw + i * DM, hn);
    // xz = hn @ in_proj^T        (M x 3072, K=768)
    {
      dim3 g(M / 64, (2 * DI) / 64);
      k_gemm_nt<<<g, 256, 0, stream>>>(hn, DM, inw + (size_t)i * 2 * DI * DM,
                                       nullptr, xz, 2 * DI, 2 * DI, DM, 0, 0);
    }
    // xc = silu(conv1d(x) + cb)  (depthwise causal, width 4)
    {
      size_t n = (size_t)M * DI;
      k_conv<<<(int)((n + 255) / 256), 256, 0, stream>>>(xz, cw + i * DI * DC,
                                                         cb + i * DI, xc);
    }
    // xdbl = xc @ x_proj^T       (M x 80, K=1536)
    {
      dim3 g(M / 64, (80 + 63) / 64);
      k_gemm_nt<<<g, 256, 0, stream>>>(xc, DI, xw + (size_t)i * 80 * DI,
                                       nullptr, xdbl, 80, 80, DI, 0, 0);
    }
    // delta = softplus(xdbl[:, :48] @ dt_proj^T + dtb) -> stored into dead x-half of xz
    {
      dim3 g(M / 64, DI / 64);
      k_gemm_nt<<<g, 256, 0, stream>>>(xdbl, 80, dtw + (size_t)i * DI * DR,
                                       dtb + i * DI, xz, 2 * DI, DI, DR, 1, 0);
    }
    // selective scan + y*silu(z), in place over xc
    k_scan<<<(Bc * DI) / 16, 256, 0, stream>>>(xz, xdbl, xz,
                                               alog + (size_t)i * DI * DS,
                                               dsk + i * DI, xc);
    // h += xc @ out_proj^T       (M x 768, K=1536)
    {
      dim3 g(M / 64, DM / 64);
      k_gemm_nt<<<g, 256, 0, stream>>>(xc, DI, ow + (size_t)i * DM * DI,
                                       nullptr, h, DM, DM, DI, 0, 1);
    }
  }

  k_rmsnorm<<<M, 256, 0, stream>>>(h, nfw, hn);
  // logits = hn @ embed^T        (M x 1969, K=768)
  {
    dim3 g(M / 64, (VOC + 63) / 64);
    k_gemm_nt<<<g, 256, 0, stream>>>(hn, DM, emb, nullptr, out, VOC, VOC, DM, 0, 0);
  }
}

// Round 2
// 9120.132 us; speedup vs baseline: 1.7565x; 1.7565x over previous
//
#include <hip/hip_runtime.h>
#include <hip/hip_bf16.h>
#include <math.h>

namespace {

constexpr int Bc  = 8;
constexpr int Lc  = 2048;
constexpr int VOC = 1969;
constexpr int DM  = 768;
constexpr int DI  = 1536;
constexpr int DS  = 16;
constexpr int DC  = 4;
constexpr int DR  = 48;
constexpr int M   = Bc * Lc;          // 16384 rows
constexpr int NC  = 32;               // scan chunks
constexpr int CT  = Lc / NC;          // 64 timesteps per chunk
constexpr float EPS_ = 1e-5f;

__device__ __forceinline__ float siluf(float x) { return x / (1.f + __expf(-x)); }

// h[row,d] = embed[ids[row]][d] + times[row]*time_w[d] + time_b[d]
__global__ void k_embed(const int* __restrict__ ids, const float* __restrict__ times,
                        const float* __restrict__ emb, const float* __restrict__ tw,
                        const float* __restrict__ tb, float* __restrict__ h) {
  int row = blockIdx.x;
  int id  = ids[row];
  float tv = times[row];
  const float* e = emb + (size_t)id * DM;
  for (int d = threadIdx.x; d < DM; d += blockDim.x)
    h[(size_t)row * DM + d] = e[d] + tv * tw[d] + tb[d];
}

// o[row,:] = x[row,:] * rsqrt(mean(x^2)+eps) * w
__global__ __launch_bounds__(256) void k_rmsnorm(const float* __restrict__ x,
                                                 const float* __restrict__ w,
                                                 float* __restrict__ o) {
  int row = blockIdx.x;
  const float* xr = x + (size_t)row * DM;
  float v[3];
  float s = 0.f;
#pragma unroll
  for (int i = 0; i < 3; i++) { v[i] = xr[threadIdx.x + 256 * i]; s += v[i] * v[i]; }
#pragma unroll
  for (int off = 32; off > 0; off >>= 1) s += __shfl_down(s, off);
  __shared__ float red[4];
  int lane = threadIdx.x & 63, wv = threadIdx.x >> 6;
  if (lane == 0) red[wv] = s;
  __syncthreads();
  if (threadIdx.x == 0)
    red[0] = rsqrtf((red[0] + red[1] + red[2] + red[3]) / (float)DM + EPS_);
  __syncthreads();
  float sc = red[0];
#pragma unroll
  for (int i = 0; i < 3; i++) {
    int d = threadIdx.x + 256 * i;
    o[(size_t)row * DM + d] = v[i] * sc * w[d];
  }
}

// Depthwise causal conv (width 4) + bias + silu.
__global__ __launch_bounds__(256) void k_conv(const float* __restrict__ xz,
                                              const float* __restrict__ cwt,
                                              const float* __restrict__ cbv,
                                              float* __restrict__ xo) {
  size_t idx = (size_t)blockIdx.x * blockDim.x + threadIdx.x;
  if (idx >= (size_t)M * DI) return;
  int d = (int)(idx % DI);
  size_t row = idx / DI;
  int t = (int)(row % Lc);
  size_t b = row / Lc;
  float acc = cbv[d];
#pragma unroll
  for (int j = 0; j < DC; j++) {
    int tt = t - (DC - 1) + j;
    if (tt >= 0) acc += cwt[d * DC + j] * xz[((size_t)b * Lc + tt) * (2 * DI) + d];
  }
  xo[idx] = siluf(acc);
}

// C[M x N] = act( A[M x K] * W[N x K]^T + bias ), optional += into C.
__global__ __launch_bounds__(256) void k_gemm_nt(
    const float* __restrict__ A, int lda,
    const float* __restrict__ W,
    const float* __restrict__ bias,
    float* __restrict__ C, int ldc,
    int N, int K, int act, int resAdd) {
  __shared__ float As[16][68];
  __shared__ float Ws[16][68];
  int tid = threadIdx.x;
  int bm = blockIdx.x << 6, bn = blockIdx.y << 6;
  int tx = tid & 15, ty = tid >> 4;
  int lrow = tid >> 2, lkk = (tid & 3) << 2;
  const float* Ap = A + (size_t)(bm + lrow) * lda + lkk;
  bool wok = (bn + lrow) < N;
  const float* Wp = W + (size_t)(bn + lrow) * K + lkk;
  float acc[4][4] = {};
  for (int k0 = 0; k0 < K; k0 += 16) {
    float4 av = *(const float4*)(Ap + k0);
    float4 wv = wok ? *(const float4*)(Wp + k0) : make_float4(0.f, 0.f, 0.f, 0.f);
    As[lkk + 0][lrow] = av.x; As[lkk + 1][lrow] = av.y;
    As[lkk + 2][lrow] = av.z; As[lkk + 3][lrow] = av.w;
    Ws[lkk + 0][lrow] = wv.x; Ws[lkk + 1][lrow] = wv.y;
    Ws[lkk + 2][lrow] = wv.z; Ws[lkk + 3][lrow] = wv.w;
    __syncthreads();
#pragma unroll
    for (int k = 0; k < 16; k++) {
      float a[4], b[4];
#pragma unroll
      for (int i = 0; i < 4; i++) a[i] = As[k][ty * 4 + i];
#pragma unroll
      for (int j = 0; j < 4; j++) b[j] = Ws[k][tx * 4 + j];
#pragma unroll
      for (int i = 0; i < 4; i++)
#pragma unroll
        for (int j = 0; j < 4; j++) acc[i][j] += a[i] * b[j];
    }
    __syncthreads();
  }
#pragma unroll
  for (int i = 0; i < 4; i++) {
    int m = bm + ty * 4 + i;
#pragma unroll
    for (int j = 0; j < 4; j++) {
      int n = bn + tx * 4 + j;
      if (n < N) {
        float v = acc[i][j];
        if (bias) v += bias[n];
        if (act == 1) v = (v > 20.f) ? v : log1pf(__expf(v));  // softplus
        size_t off = (size_t)m * ldc + n;
        if (resAdd) C[off] += v; else C[off] = v;
      }
    }
  }
}

// ---------------- chunked selective scan ----------------
// Scratch layout: sc[((b*NC + c)*DI + d)*32 + n]   = local final h (pass1) -> h_in (pass2)
//                 sc[((b*NC + c)*DI + d)*32 + 16+n] = chunk decay product P
// Pass 1: per (b,chunk,d) local scan with h_in = 0; record h_fin and P.
__global__ __launch_bounds__(256) void k_scan1(
    const float* __restrict__ xz,     // delta at [row*3072 + d]
    const float* __restrict__ u_xc,   // [M][DI]
    const float* __restrict__ xdbl,   // [M][80]: B at 48+n
    const float* __restrict__ alog,   // [DI][16]
    float* __restrict__ sc) {
  __shared__ float bcs[CT][32];
  int b = blockIdx.z, c = blockIdx.y;
  int d = blockIdx.x * 256 + threadIdx.x;
  int row0 = b * Lc + c * CT;
  // stage B (and C, unused) for this chunk
#pragma unroll
  for (int k = 0; k < (CT * 32) / 256; k++) {
    int i = k * 256 + threadIdx.x;
    int t = i >> 5, j = i & 31;
    bcs[t][j] = xdbl[(size_t)(row0 + t) * 80 + 48 + j];
  }
  float Av[16];
#pragma unroll
  for (int n = 0; n < 16; n++) Av[n] = -__expf(alog[d * DS + n]);
  float h[16], P[16];
#pragma unroll
  for (int n = 0; n < 16; n++) { h[n] = 0.f; P[n] = 1.f; }
  __syncthreads();
  for (int t = 0; t < CT; t++) {
    size_t row = row0 + t;
    float dlt = xz[row * (2 * DI) + d];
    float u   = u_xc[row * DI + d];
    float du  = dlt * u;
#pragma unroll
    for (int n = 0; n < 16; n++) {
      float e = __expf(dlt * Av[n]);
      h[n] = h[n] * e + du * bcs[t][n];
      P[n] *= e;
    }
  }
  float* o = sc + (((size_t)b * NC + c) * DI + d) * 32;
#pragma unroll
  for (int n = 0; n < 16; n += 4) {
    *(float4*)(o + n)      = make_float4(h[n], h[n + 1], h[n + 2], h[n + 3]);
    *(float4*)(o + 16 + n) = make_float4(P[n], P[n + 1], P[n + 2], P[n + 3]);
  }
}

// Pass 2: sequential combine over chunks; overwrite h slot with incoming state h_in.
__global__ __launch_bounds__(256) void k_scan2(float* __restrict__ sc) {
  int g = blockIdx.x * 256 + threadIdx.x;        // g < B*DI*16
  int n = g & 15;
  int rest = g >> 4;
  int d = rest % DI;
  int b = rest / DI;
  float cur = 0.f;
  for (int c = 0; c < NC; c++) {
    float* p = sc + (((size_t)b * NC + c) * DI + d) * 32;
    float hf = p[n];
    float pd = p[16 + n];
    p[n] = cur;                 // h_in for chunk c
    cur = pd * cur + hf;
  }
}

// Pass 3: re-scan each chunk from h_in, y = C.h + u*D, out = y*silu(z) (in place over u).
__global__ __launch_bounds__(256) void k_scan3(
    const float* __restrict__ xz,     // delta at d, z at DI+d
    float* __restrict__ u_xc,         // in: u, out: y*silu(z)
    const float* __restrict__ xdbl,   // B at 48+n, C at 64+n
    const float* __restrict__ alog,
    const float* __restrict__ dsk,
    const float* __restrict__ sc) {
  __shared__ float bcs[CT][32];
  int b = blockIdx.z, c = blockIdx.y;
  int d = blockIdx.x * 256 + threadIdx.x;
  int row0 = b * Lc + c * CT;
#pragma unroll
  for (int k = 0; k < (CT * 32) / 256; k++) {
    int i = k * 256 + threadIdx.x;
    int t = i >> 5, j = i & 31;
    bcs[t][j] = xdbl[(size_t)(row0 + t) * 80 + 48 + j];
  }
  float Av[16];
#pragma unroll
  for (int n = 0; n < 16; n++) Av[n] = -__expf(alog[d * DS + n]);
  float Dv = dsk[d];
  float h[16];
  const float* ip = sc + (((size_t)b * NC + c) * DI + d) * 32;
#pragma unroll
  for (int n = 0; n < 16; n += 4) {
    float4 v = *(const float4*)(ip + n);
    h[n] = v.x; h[n + 1] = v.y; h[n + 2] = v.z; h[n + 3] = v.w;
  }
  __syncthreads();
  for (int t = 0; t < CT; t++) {
    size_t row = row0 + t;
    float dlt = xz[row * (2 * DI) + d];
    float u   = u_xc[row * DI + d];
    float du  = dlt * u;
    float y = 0.f;
#pragma unroll
    for (int n = 0; n < 16; n++) {
      float e = __expf(dlt * Av[n]);
      h[n] = h[n] * e + du * bcs[t][n];
      y += h[n] * bcs[t][16 + n];
    }
    y += u * Dv;
    float z = xz[row * (2 * DI) + DI + d];
    u_xc[row * DI + d] = y * siluf(z);
  }
}

}  // namespace

extern "C" void kernel_launch(void* const* d_in, const int* in_sizes, int n_in,
                              void* d_out, int out_size, void* d_ws, size_t ws_size,
                              hipStream_t stream) {
  const int*   ids   = (const int*)d_in[0];
  const float* times = (const float*)d_in[1];
  const float* emb   = (const float*)d_in[3];
  const float* tw    = (const float*)d_in[4];
  const float* tb    = (const float*)d_in[5];
  const float* inw   = (const float*)d_in[6];
  const float* cw    = (const float*)d_in[7];
  const float* cb    = (const float*)d_in[8];
  const float* xw    = (const float*)d_in[9];
  const float* dtw   = (const float*)d_in[10];
  const float* dtb   = (const float*)d_in[11];
  const float* alog  = (const float*)d_in[12];
  const float* dsk   = (const float*)d_in[13];
  const float* ow    = (const float*)d_in[14];
  const float* nw    = (const float*)d_in[15];
  const float* nfw   = (const float*)d_in[16];
  float* out = (float*)d_out;

  float* ws   = (float*)d_ws;
  float* h    = ws;  ws += (size_t)M * DM;
  float* hn   = ws;  ws += (size_t)M * DM;
  float* xz   = ws;  ws += (size_t)M * (2 * DI);
  float* xc   = ws;  ws += (size_t)M * DI;
  float* xdbl = ws;  ws += (size_t)M * (DR + 2 * DS);
  float* scb  = ws;  ws += (size_t)Bc * NC * DI * 32;   // chunk summaries (50 MB)

  k_embed<<<M, 256, 0, stream>>>(ids, times, emb, tw, tb, h);

  for (int i = 0; i < 4; i++) {
    k_rmsnorm<<<M, 256, 0, stream>>>(h, nw + i * DM, hn);
    {  // xz = hn @ in_proj^T
      dim3 g(M / 64, (2 * DI) / 64);
      k_gemm_nt<<<g, 256, 0, stream>>>(hn, DM, inw + (size_t)i * 2 * DI * DM,
                                       nullptr, xz, 2 * DI, 2 * DI, DM, 0, 0);
    }
    {  // xc = silu(conv1d(x) + cb)
      size_t n = (size_t)M * DI;
      k_conv<<<(int)((n + 255) / 256), 256, 0, stream>>>(xz, cw + i * DI * DC,
                                                         cb + i * DI, xc);
    }
    {  // xdbl = xc @ x_proj^T
      dim3 g(M / 64, (80 + 63) / 64);
      k_gemm_nt<<<g, 256, 0, stream>>>(xc, DI, xw + (size_t)i * 80 * DI,
                                       nullptr, xdbl, 80, 80, DI, 0, 0);
    }
    {  // delta = softplus(xdbl[:, :48] @ dt_proj^T + dtb) -> x-half of xz
      dim3 g(M / 64, DI / 64);
      k_gemm_nt<<<g, 256, 0, stream>>>(xdbl, 80, dtw + (size_t)i * DI * DR,
                                       dtb + i * DI, xz, 2 * DI, DI, DR, 1, 0);
    }
    {  // chunked selective scan + y*silu(z) fused, in place over xc
      dim3 g1(DI / 256, NC, Bc);
      k_scan1<<<g1, 256, 0, stream>>>(xz, xc, xdbl, alog + (size_t)i * DI * DS, scb);
      k_scan2<<<(Bc * DI * DS) / 256, 256, 0, stream>>>(scb);
      k_scan3<<<g1, 256, 0, stream>>>(xz, xc, xdbl, alog + (size_t)i * DI * DS,
                                      dsk + i * DI, scb);
    }
    {  // h += xc @ out_proj^T
      dim3 g(M / 64, DM / 64);
      k_gemm_nt<<<g, 256, 0, stream>>>(xc, DI, ow + (size_t)i * DM * DI,
                                       nullptr, h, DM, DM, DI, 0, 1);
    }
  }

  k_rmsnorm<<<M, 256, 0, stream>>>(h, nfw, hn);
  {  // logits = hn @ embed^T
    dim3 g(M / 64, (VOC + 63) / 64);
    k_gemm_nt<<<g, 256, 0, stream>>>(hn, DM, emb, nullptr, out, VOC, VOC, DM, 0, 0);
  }
}

// Round 3
// 3082.548 us; speedup vs baseline: 5.1967x; 2.9586x over previous
//
#include <hip/hip_runtime.h>
#include <hip/hip_bf16.h>
#include <math.h>

namespace {

constexpr int Bc  = 8;
constexpr int Lc  = 2048;
constexpr int VOC = 1969;
constexpr int DM  = 768;
constexpr int DI  = 1536;
constexpr int DS  = 16;
constexpr int DC  = 4;
constexpr int DR  = 48;
constexpr int M   = Bc * Lc;          // 16384 rows
constexpr int NC  = 32;               // scan chunks
constexpr int CT  = Lc / NC;          // 64 timesteps per chunk
constexpr float EPS_ = 1e-5f;

typedef __bf16 bf16x8 __attribute__((ext_vector_type(8)));
typedef float  f32x4  __attribute__((ext_vector_type(4)));

__device__ __forceinline__ float siluf(float x) { return x / (1.f + __expf(-x)); }

// -------- f32 -> bf16 conversion (weights / embed), vectorized --------
__global__ __launch_bounds__(256) void k_f2b(const float* __restrict__ in,
                                             __bf16* __restrict__ out, int n4) {
  // n4 = count/4 ; processes 4 elems per thread, grid-stride
  for (int i = blockIdx.x * 256 + threadIdx.x; i < n4; i += gridDim.x * 256) {
    float4 v = *(const float4*)(in + (size_t)i * 4);
    __bf16* o = out + (size_t)i * 4;
    o[0] = (__bf16)v.x; o[1] = (__bf16)v.y; o[2] = (__bf16)v.z; o[3] = (__bf16)v.w;
  }
}

// h[row,d] = embed[ids[row]][d] + times[row]*time_w[d] + time_b[d]
__global__ void k_embed(const int* __restrict__ ids, const float* __restrict__ times,
                        const float* __restrict__ emb, const float* __restrict__ tw,
                        const float* __restrict__ tb, float* __restrict__ h) {
  int row = blockIdx.x;
  int id  = ids[row];
  float tv = times[row];
  const float* e = emb + (size_t)id * DM;
  for (int d = threadIdx.x; d < DM; d += blockDim.x)
    h[(size_t)row * DM + d] = e[d] + tv * tw[d] + tb[d];
}

// bf16 out: o[row,:] = x[row,:] * rsqrt(mean(x^2)+eps) * w
__global__ __launch_bounds__(256) void k_rmsnorm(const float* __restrict__ x,
                                                 const float* __restrict__ w,
                                                 __bf16* __restrict__ o) {
  int row = blockIdx.x;
  const float* xr = x + (size_t)row * DM;
  float v[3];
  float s = 0.f;
#pragma unroll
  for (int i = 0; i < 3; i++) { v[i] = xr[threadIdx.x + 256 * i]; s += v[i] * v[i]; }
#pragma unroll
  for (int off = 32; off > 0; off >>= 1) s += __shfl_down(s, off);
  __shared__ float red[4];
  int lane = threadIdx.x & 63, wv = threadIdx.x >> 6;
  if (lane == 0) red[wv] = s;
  __syncthreads();
  if (threadIdx.x == 0)
    red[0] = rsqrtf((red[0] + red[1] + red[2] + red[3]) / (float)DM + EPS_);
  __syncthreads();
  float sc = red[0];
#pragma unroll
  for (int i = 0; i < 3; i++) {
    int d = threadIdx.x + 256 * i;
    o[(size_t)row * DM + d] = (__bf16)(v[i] * sc * w[d]);
  }
}

// Depthwise causal conv (width 4) + bias + silu ; bf16 out.
__global__ __launch_bounds__(256) void k_conv(const float* __restrict__ xz,
                                              const float* __restrict__ cwt,
                                              const float* __restrict__ cbv,
                                              __bf16* __restrict__ xo) {
  size_t idx = (size_t)blockIdx.x * blockDim.x + threadIdx.x;
  if (idx >= (size_t)M * DI) return;
  int d = (int)(idx % DI);
  size_t row = idx / DI;
  int t = (int)(row % Lc);
  size_t b = row / Lc;
  float acc = cbv[d];
#pragma unroll
  for (int j = 0; j < DC; j++) {
    int tt = t - (DC - 1) + j;
    if (tt >= 0) acc += cwt[d * DC + j] * xz[((size_t)b * Lc + tt) * (2 * DI) + d];
  }
  xo[idx] = (__bf16)siluf(acc);
}

// ---------------- bf16 MFMA GEMM:  C[M x N] (+)= A[M x K] * W[N x K]^T ----------------
// 128x128 tile, BK=32, 256 threads = 4 waves in 2x2, 64x64 per wave.
// mfma_f32_16x16x32_bf16: A-frag lane l: row=l&15, k=8*(l>>4)+e ; C/D: col=lane&15,
// row=(lane>>4)*4+reg  (learn_hip m89-verified). LDS slot swizzle: s'=(s+row+(row>>2))&3.
__global__ __launch_bounds__(256) void k_gemm_mfma(
    const __bf16* __restrict__ A,
    const __bf16* __restrict__ W,
    float* __restrict__ C, int ldc,
    int N, int K, int resAdd) {
  __shared__ __bf16 As[128 * 32];
  __shared__ __bf16 Bs[128 * 32];
  int tid = threadIdx.x;
  int l = tid & 63, w = tid >> 6;
  int wr = w >> 1, wc = w & 1;
  int bm = blockIdx.x << 7, bn = blockIdx.y << 7;

  // staging: chunk c in [0,512): row=c>>2, slot=c&3; this thread does c=tid, tid+256
  int srow = tid >> 2, sslot = tid & 3;
  size_t kbytes = (size_t)K * 2;
  const char* ap0 = (const char*)A + (size_t)(bm + srow) * kbytes + sslot * 16;
  const char* ap1 = ap0 + 64 * kbytes;
  int wr0 = bn + srow;        if (wr0 > N - 1) wr0 = N - 1;
  int wr1 = bn + srow + 64;   if (wr1 > N - 1) wr1 = N - 1;
  const char* wp0 = (const char*)W + (size_t)wr0 * kbytes + sslot * 16;
  const char* wp1 = (const char*)W + (size_t)wr1 * kbytes + sslot * 16;
  int so = srow * 64 + (((sslot + srow + (srow >> 2)) & 3) << 4);   // bytes; row+64 same slot
  char* asw0 = (char*)As + so;  char* asw1 = asw0 + 64 * 64;
  char* bsw0 = (char*)Bs + so;  char* bsw1 = bsw0 + 64 * 64;

  // fragment read offsets (bytes), constant across K-steps
  int aoff[4], boff[4];
#pragma unroll
  for (int i = 0; i < 4; i++) {
    int ra = wr * 64 + i * 16 + (l & 15);
    aoff[i] = ra * 64 + ((((l >> 4) + ra + (ra >> 2)) & 3) << 4);
    int rb = wc * 64 + i * 16 + (l & 15);
    boff[i] = rb * 64 + ((((l >> 4) + rb + (rb >> 2)) & 3) << 4);
  }

  f32x4 acc[4][4];
#pragma unroll
  for (int i = 0; i < 4; i++)
#pragma unroll
    for (int j = 0; j < 4; j++)
#pragma unroll
      for (int e = 0; e < 4; e++) acc[i][j][e] = 0.f;

  for (int k0 = 0; k0 < K; k0 += 32) {
    size_t kb = (size_t)k0 * 2;
    ulonglong2 a0 = *(const ulonglong2*)(ap0 + kb);
    ulonglong2 a1 = *(const ulonglong2*)(ap1 + kb);
    ulonglong2 b0 = *(const ulonglong2*)(wp0 + kb);
    ulonglong2 b1 = *(const ulonglong2*)(wp1 + kb);
    __syncthreads();                       // previous tile fully consumed
    *(ulonglong2*)asw0 = a0;  *(ulonglong2*)asw1 = a1;
    *(ulonglong2*)bsw0 = b0;  *(ulonglong2*)bsw1 = b1;
    __syncthreads();
    bf16x8 af[4], bfr[4];
#pragma unroll
    for (int i = 0; i < 4; i++) {
      af[i]  = *(const bf16x8*)((const char*)As + aoff[i]);
      bfr[i] = *(const bf16x8*)((const char*)Bs + boff[i]);
    }
#pragma unroll
    for (int i = 0; i < 4; i++)
#pragma unroll
      for (int j = 0; j < 4; j++)
        acc[i][j] = __builtin_amdgcn_mfma_f32_16x16x32_bf16(af[i], bfr[j], acc[i][j], 0, 0, 0);
  }

#pragma unroll
  for (int i = 0; i < 4; i++) {
#pragma unroll
    for (int r = 0; r < 4; r++) {
      int grow = bm + wr * 64 + i * 16 + (l >> 4) * 4 + r;
#pragma unroll
      for (int j = 0; j < 4; j++) {
        int gcol = bn + wc * 64 + j * 16 + (l & 15);
        if (gcol < N) {
          size_t off = (size_t)grow * ldc + gcol;
          float v = acc[i][j][r];
          C[off] = resAdd ? C[off] + v : v;
        }
      }
    }
  }
}

// f32 fallback GEMM (dt_proj only): C = act(A*W^T + bias)
__global__ __launch_bounds__(256) void k_gemm_nt(
    const float* __restrict__ A, int lda,
    const float* __restrict__ W,
    const float* __restrict__ bias,
    float* __restrict__ C, int ldc,
    int N, int K, int act, int resAdd) {
  __shared__ float As[16][68];
  __shared__ float Ws[16][68];
  int tid = threadIdx.x;
  int bm = blockIdx.x << 6, bn = blockIdx.y << 6;
  int tx = tid & 15, ty = tid >> 4;
  int lrow = tid >> 2, lkk = (tid & 3) << 2;
  const float* Ap = A + (size_t)(bm + lrow) * lda + lkk;
  bool wok = (bn + lrow) < N;
  const float* Wp = W + (size_t)(bn + lrow) * K + lkk;
  float acc[4][4] = {};
  for (int k0 = 0; k0 < K; k0 += 16) {
    float4 av = *(const float4*)(Ap + k0);
    float4 wv = wok ? *(const float4*)(Wp + k0) : make_float4(0.f, 0.f, 0.f, 0.f);
    As[lkk + 0][lrow] = av.x; As[lkk + 1][lrow] = av.y;
    As[lkk + 2][lrow] = av.z; As[lkk + 3][lrow] = av.w;
    Ws[lkk + 0][lrow] = wv.x; Ws[lkk + 1][lrow] = wv.y;
    Ws[lkk + 2][lrow] = wv.z; Ws[lkk + 3][lrow] = wv.w;
    __syncthreads();
#pragma unroll
    for (int k = 0; k < 16; k++) {
      float a[4], b[4];
#pragma unroll
      for (int i = 0; i < 4; i++) a[i] = As[k][ty * 4 + i];
#pragma unroll
      for (int j = 0; j < 4; j++) b[j] = Ws[k][tx * 4 + j];
#pragma unroll
      for (int i = 0; i < 4; i++)
#pragma unroll
        for (int j = 0; j < 4; j++) acc[i][j] += a[i] * b[j];
    }
    __syncthreads();
  }
#pragma unroll
  for (int i = 0; i < 4; i++) {
    int m = bm + ty * 4 + i;
#pragma unroll
    for (int j = 0; j < 4; j++) {
      int n = bn + tx * 4 + j;
      if (n < N) {
        float v = acc[i][j];
        if (bias) v += bias[n];
        if (act == 1) v = (v > 20.f) ? v : log1pf(__expf(v));  // softplus
        size_t off = (size_t)m * ldc + n;
        if (resAdd) C[off] += v; else C[off] = v;
      }
    }
  }
}

// ---------------- chunked selective scan (u in bf16) ----------------
__global__ __launch_bounds__(256) void k_scan1(
    const float* __restrict__ xz,       // delta at [row*3072 + d]
    const __bf16* __restrict__ u_xc,    // [M][DI]
    const float* __restrict__ xdbl,     // [M][80]: B at 48+n
    const float* __restrict__ alog,
    float* __restrict__ sc) {
  __shared__ float bcs[CT][32];
  int b = blockIdx.z, c = blockIdx.y;
  int d = blockIdx.x * 256 + threadIdx.x;
  int row0 = b * Lc + c * CT;
#pragma unroll
  for (int k = 0; k < (CT * 32) / 256; k++) {
    int i = k * 256 + threadIdx.x;
    int t = i >> 5, j = i & 31;
    bcs[t][j] = xdbl[(size_t)(row0 + t) * 80 + 48 + j];
  }
  float Av[16];
#pragma unroll
  for (int n = 0; n < 16; n++) Av[n] = -__expf(alog[d * DS + n]);
  float h[16], P[16];
#pragma unroll
  for (int n = 0; n < 16; n++) { h[n] = 0.f; P[n] = 1.f; }
  __syncthreads();
  for (int t = 0; t < CT; t++) {
    size_t row = row0 + t;
    float dlt = xz[row * (2 * DI) + d];
    float u   = (float)u_xc[row * DI + d];
    float du  = dlt * u;
#pragma unroll
    for (int n = 0; n < 16; n++) {
      float e = __expf(dlt * Av[n]);
      h[n] = h[n] * e + du * bcs[t][n];
      P[n] *= e;
    }
  }
  float* o = sc + (((size_t)b * NC + c) * DI + d) * 32;
#pragma unroll
  for (int n = 0; n < 16; n += 4) {
    *(float4*)(o + n)      = make_float4(h[n], h[n + 1], h[n + 2], h[n + 3]);
    *(float4*)(o + 16 + n) = make_float4(P[n], P[n + 1], P[n + 2], P[n + 3]);
  }
}

__global__ __launch_bounds__(256) void k_scan2(float* __restrict__ sc) {
  int g = blockIdx.x * 256 + threadIdx.x;
  int n = g & 15;
  int rest = g >> 4;
  int d = rest % DI;
  int b = rest / DI;
  float cur = 0.f;
  for (int c = 0; c < NC; c++) {
    float* p = sc + (((size_t)b * NC + c) * DI + d) * 32;
    float hf = p[n];
    float pd = p[16 + n];
    p[n] = cur;
    cur = pd * cur + hf;
  }
}

__global__ __launch_bounds__(256) void k_scan3(
    const float* __restrict__ xz,       // delta at d, z at DI+d
    __bf16* __restrict__ u_xc,          // in: u, out: y*silu(z)  (bf16)
    const float* __restrict__ xdbl,     // B at 48+n, C at 64+n
    const float* __restrict__ alog,
    const float* __restrict__ dsk,
    const float* __restrict__ sc) {
  __shared__ float bcs[CT][32];
  int b = blockIdx.z, c = blockIdx.y;
  int d = blockIdx.x * 256 + threadIdx.x;
  int row0 = b * Lc + c * CT;
#pragma unroll
  for (int k = 0; k < (CT * 32) / 256; k++) {
    int i = k * 256 + threadIdx.x;
    int t = i >> 5, j = i & 31;
    bcs[t][j] = xdbl[(size_t)(row0 + t) * 80 + 48 + j];
  }
  float Av[16];
#pragma unroll
  for (int n = 0; n < 16; n++) Av[n] = -__expf(alog[d * DS + n]);
  float Dv = dsk[d];
  float h[16];
  const float* ip = sc + (((size_t)b * NC + c) * DI + d) * 32;
#pragma unroll
  for (int n = 0; n < 16; n += 4) {
    float4 v = *(const float4*)(ip + n);
    h[n] = v.x; h[n + 1] = v.y; h[n + 2] = v.z; h[n + 3] = v.w;
  }
  __syncthreads();
  for (int t = 0; t < CT; t++) {
    size_t row = row0 + t;
    float dlt = xz[row * (2 * DI) + d];
    float u   = (float)u_xc[row * DI + d];
    float du  = dlt * u;
    float y = 0.f;
#pragma unroll
    for (int n = 0; n < 16; n++) {
      float e = __expf(dlt * Av[n]);
      h[n] = h[n] * e + du * bcs[t][n];
      y += h[n] * bcs[t][16 + n];
    }
    y += u * Dv;
    float z = xz[row * (2 * DI) + DI + d];
    u_xc[row * DI + d] = (__bf16)(y * siluf(z));
  }
}

}  // namespace

extern "C" void kernel_launch(void* const* d_in, const int* in_sizes, int n_in,
                              void* d_out, int out_size, void* d_ws, size_t ws_size,
                              hipStream_t stream) {
  const int*   ids   = (const int*)d_in[0];
  const float* times = (const float*)d_in[1];
  const float* emb   = (const float*)d_in[3];
  const float* tw    = (const float*)d_in[4];
  const float* tb    = (const float*)d_in[5];
  const float* inw   = (const float*)d_in[6];
  const float* cw    = (const float*)d_in[7];
  const float* cb    = (const float*)d_in[8];
  const float* xw    = (const float*)d_in[9];
  const float* dtw   = (const float*)d_in[10];
  const float* dtb   = (const float*)d_in[11];
  const float* alog  = (const float*)d_in[12];
  const float* dsk   = (const float*)d_in[13];
  const float* ow    = (const float*)d_in[14];
  const float* nw    = (const float*)d_in[15];
  const float* nfw   = (const float*)d_in[16];
  float* out = (float*)d_out;

  // ---- workspace layout: f32 regions first, then bf16 (all 16B-aligned) ----
  float* wsf  = (float*)d_ws;
  float* h    = wsf;  wsf += (size_t)M * DM;                 // 50.3 MB
  float* xz   = wsf;  wsf += (size_t)M * (2 * DI);           // 201.3 MB
  float* xdbl = wsf;  wsf += (size_t)M * (DR + 2 * DS);      // 5.2 MB
  float* scb  = wsf;  wsf += (size_t)Bc * NC * DI * 32;      // 50.3 MB
  __bf16* wsb = (__bf16*)wsf;
  __bf16* hnb  = wsb;  wsb += (size_t)M * DM;                // 25.2 MB
  __bf16* xcb  = wsb;  wsb += (size_t)M * DI;                // 50.3 MB
  __bf16* ebw  = wsb;  wsb += (size_t)VOC * DM;              // 3.0 MB
  __bf16* inwb = wsb;  wsb += (size_t)4 * 2 * DI * DM;       // 18.9 MB
  __bf16* xwb  = wsb;  wsb += (size_t)4 * 80 * DI;           // 1.0 MB
  __bf16* owb  = wsb;  wsb += (size_t)4 * DM * DI;           // 9.4 MB

  // weight / embed conversions (every call; deterministic)
  k_f2b<<<2048, 256, 0, stream>>>(emb, ebw, (VOC * DM) / 4);
  k_f2b<<<2048, 256, 0, stream>>>(inw, inwb, (4 * 2 * DI * DM) / 4);
  k_f2b<<<1024, 256, 0, stream>>>(xw,  xwb,  (4 * 80 * DI) / 4);
  k_f2b<<<2048, 256, 0, stream>>>(ow,  owb,  (4 * DM * DI) / 4);

  k_embed<<<M, 256, 0, stream>>>(ids, times, emb, tw, tb, h);

  for (int i = 0; i < 4; i++) {
    k_rmsnorm<<<M, 256, 0, stream>>>(h, nw + i * DM, hnb);
    {  // xz = hn @ in_proj^T   (bf16 MFMA)
      dim3 g(M / 128, (2 * DI) / 128);
      k_gemm_mfma<<<g, 256, 0, stream>>>(hnb, inwb + (size_t)i * 2 * DI * DM,
                                         xz, 2 * DI, 2 * DI, DM, 0);
    }
    {  // xcb = silu(conv1d(x) + cb)  -> bf16
      size_t n = (size_t)M * DI;
      k_conv<<<(int)((n + 255) / 256), 256, 0, stream>>>(xz, cw + i * DI * DC,
                                                         cb + i * DI, xcb);
    }
    {  // xdbl = xc @ x_proj^T  (bf16 MFMA, N=80 via clamp)
      dim3 g(M / 128, 1);
      k_gemm_mfma<<<g, 256, 0, stream>>>(xcb, xwb + (size_t)i * 80 * DI,
                                         xdbl, 80, 80, DI, 0);
    }
    {  // delta = softplus(xdbl[:, :48] @ dt_proj^T + dtb) -> x-half of xz (f32 path)
      dim3 g(M / 64, DI / 64);
      k_gemm_nt<<<g, 256, 0, stream>>>(xdbl, 80, dtw + (size_t)i * DI * DR,
                                       dtb + i * DI, xz, 2 * DI, DI, DR, 1, 0);
    }
    {  // chunked selective scan + y*silu(z) fused, in place over xcb
      dim3 g1(DI / 256, NC, Bc);
      k_scan1<<<g1, 256, 0, stream>>>(xz, xcb, xdbl, alog + (size_t)i * DI * DS, scb);
      k_scan2<<<(Bc * DI * DS) / 256, 256, 0, stream>>>(scb);
      k_scan3<<<g1, 256, 0, stream>>>(xz, xcb, xdbl, alog + (size_t)i * DI * DS,
                                      dsk + i * DI, scb);
    }
    {  // h += y @ out_proj^T   (bf16 MFMA, resAdd)
      dim3 g(M / 128, DM / 128);
      k_gemm_mfma<<<g, 256, 0, stream>>>(xcb, owb + (size_t)i * DM * DI,
                                         h, DM, DM, DI, 1);
    }
  }

  k_rmsnorm<<<M, 256, 0, stream>>>(h, nfw, hnb);
  {  // logits = hn @ embed^T   (bf16 MFMA, N=1969 via clamp+guard)
    dim3 g(M / 128, (VOC + 127) / 128);
    k_gemm_mfma<<<g, 256, 0, stream>>>(hnb, ebw, out, VOC, VOC, DM, 0);
  }
}